// Round 11
// baseline (1032.672 us; speedup 1.0000x reference)
//
#include <hip/hip_runtime.h>

// ---------- types & helpers ----------
using f32x4     = __attribute__((ext_vector_type(4))) float;
using bf16x8    = __attribute__((ext_vector_type(8))) short;
using ushort4_t = __attribute__((ext_vector_type(4))) unsigned short;
using ushort8_t = __attribute__((ext_vector_type(8))) unsigned short;

__device__ __forceinline__ unsigned short f2bf(float f) {
    unsigned u = __builtin_bit_cast(unsigned, f);
    u += 0x7fffu + ((u >> 16) & 1u);   // RNE
    return (unsigned short)(u >> 16);
}
__device__ __forceinline__ float bf2f(unsigned short h) {
    return __builtin_bit_cast(float, (unsigned)h << 16);
}

__device__ __forceinline__ float wave_sum(float v) {
#pragma unroll
    for (int off = 32; off > 0; off >>= 1) v += __shfl_xor(v, off, 64);
    return v;
}
__device__ __forceinline__ float wave_max(float v) {
#pragma unroll
    for (int off = 32; off > 0; off >>= 1) v = fmaxf(v, __shfl_xor(v, off, 64));
    return v;
}

#define GLP(p)  ((const __attribute__((address_space(1))) void*)(p))
#define LDSP(p) ((__attribute__((address_space(3))) void*)(p))

// ---------- dual f32 -> bf16 bulk convert (two jobs, one launch) ----------
__global__ __launch_bounds__(256) void cvt2(
    const float* __restrict__ in0, unsigned short* __restrict__ out0, long n80,
    const float* __restrict__ in1, unsigned short* __restrict__ out1, long n81, int split)
{
    const float* in; unsigned short* out; long n8, i, stride;
    if ((int)blockIdx.x < split) {
        in = in0; out = out0; n8 = n80;
        i = (long)blockIdx.x * 256 + threadIdx.x; stride = (long)split * 256;
    } else {
        in = in1; out = out1; n8 = n81;
        i = (long)(blockIdx.x - split) * 256 + threadIdx.x;
        stride = (long)(gridDim.x - split) * 256;
    }
    for (; i < n8; i += stride) {
        const float4* p = (const float4*)(in + i * 8);
        float4 a = p[0], b = p[1];
        ushort8_t v;
        v[0] = f2bf(a.x); v[1] = f2bf(a.y); v[2] = f2bf(a.z); v[3] = f2bf(a.w);
        v[4] = f2bf(b.x); v[5] = f2bf(b.y); v[6] = f2bf(b.z); v[7] = f2bf(b.w);
        *(ushort8_t*)(out + i * 8) = v;
    }
}

// ---------- coalesced LDS-tiled weight transpose -> bf16 [N][K] ----------
__global__ __launch_bounds__(256) void pack_t(
    const float* __restrict__ S0, const float* __restrict__ S1, int nsplit,
    unsigned short* __restrict__ D, int K)
{
    __shared__ float t[64][65];
    const int k0 = blockIdx.x * 64, n0 = blockIdx.y * 64;
    const float* S = (n0 < nsplit) ? S0 : S1;
    const int nb = (n0 < nsplit) ? n0 : n0 - nsplit;
    const int c = threadIdx.x & 63, r4 = threadIdx.x >> 6;
#pragma unroll
    for (int it = 0; it < 16; ++it) {
        int r = it * 4 + r4;
        t[r][c] = S[(size_t)(k0 + r) * nsplit + nb + c];
    }
    __syncthreads();
#pragma unroll
    for (int it = 0; it < 16; ++it) {
        int rn = it * 4 + r4;
        D[(size_t)(n0 + rn) * K + k0 + c] = f2bf(t[c][rn]);
    }
}

// ---------- 256x256 bf16 GEMM, 8-phase (FROZEN, R7/R8 config) ----------
template <int OUTBF>
__global__ __launch_bounds__(512, 1) void gemm8(
    const unsigned short* __restrict__ A, const unsigned short* __restrict__ Bt,
    const float* __restrict__ bias0, const float* __restrict__ bias1, int nsplit,
    void* __restrict__ Cv, int N, int K, int NTN)
{
    __shared__ unsigned short LA[2][2][8192];
    __shared__ unsigned short LB[2][2][8192];
    const int tid = threadIdx.x, lane = tid & 63, wid = tid >> 6;

    int nwg = (int)gridDim.x, bid = (int)blockIdx.x;
    if ((nwg & 7) == 0) { int cpx = nwg >> 3; bid = (bid & 7) * cpx + (bid >> 3); }  // T1
    const int tn = bid % NTN, tm = bid / NTN;
    const size_t m0 = (size_t)tm * 256, n0 = (size_t)tn * 256;
    const int NT = K >> 6;
    const int NIT = NT >> 1;

    const int wr = wid >> 2, wc = wid & 3;
    const int hb = wc >> 1;
    const int fr = lane & 15, fs = lane >> 4;

    const int r0 = tid >> 3, s0 = ((tid & 7) - r0) & 7;
    const int r1 = r0 + 64,  s1 = ((tid & 7) - r1) & 7;
    const unsigned short* pA[2][2];
    const unsigned short* pB[2][2];
#pragma unroll
    for (int h = 0; h < 2; ++h) {
        pA[h][0] = A  + (m0 + h * 128 + r0) * K + s0 * 8;
        pA[h][1] = A  + (m0 + h * 128 + r1) * K + s1 * 8;
        pB[h][0] = Bt + (n0 + h * 128 + r0) * K + s0 * 8;
        pB[h][1] = Bt + (n0 + h * 128 + r1) * K + s1 * 8;
    }
    const int d0 = tid * 8, d1 = (tid + 512) * 8;

#define STG_A(h, t, B_) do { \
    __builtin_amdgcn_global_load_lds(GLP(pA[h][0] + (size_t)(t) * 64), LDSP(&LA[B_][h][d0]), 16, 0, 0); \
    __builtin_amdgcn_global_load_lds(GLP(pA[h][1] + (size_t)(t) * 64), LDSP(&LA[B_][h][d1]), 16, 0, 0); \
} while (0)
#define STG_B(h, t, B_) do { \
    __builtin_amdgcn_global_load_lds(GLP(pB[h][0] + (size_t)(t) * 64), LDSP(&LB[B_][h][d0]), 16, 0, 0); \
    __builtin_amdgcn_global_load_lds(GLP(pB[h][1] + (size_t)(t) * 64), LDSP(&LB[B_][h][d1]), 16, 0, 0); \
} while (0)

    int offA[2][4], offB[2][2];
#pragma unroll
    for (int mq = 0; mq < 2; ++mq)
#pragma unroll
        for (int mfl = 0; mfl < 4; ++mfl) {
            int r = mq * 64 + mfl * 16 + fr;
            offA[mq][mfl] = r * 64 + ((fs + r) & 7) * 8;
        }
#pragma unroll
    for (int nq = 0; nq < 2; ++nq)
#pragma unroll
        for (int nfl = 0; nfl < 2; ++nfl) {
            int r = (wc & 1) * 64 + nq * 32 + nfl * 16 + fr;
            offB[nq][nfl] = r * 64 + ((fs + r) & 7) * 8;
        }

#define LDA_SUB(B_, mq) do { \
    _Pragma("unroll") \
    for (int mfl = 0; mfl < 4; ++mfl) { \
        av[mfl][0] = *(const bf16x8*)&LA[B_][wr][offA[mq][mfl]]; \
        av[mfl][1] = *(const bf16x8*)&LA[B_][wr][offA[mq][mfl] ^ 32]; \
    } } while (0)
#define LDB_SUB(B_, nq, bv) do { \
    _Pragma("unroll") \
    for (int nfl = 0; nfl < 2; ++nfl) { \
        bv[nfl][0] = *(const bf16x8*)&LB[B_][hb][offB[nq][nfl]]; \
        bv[nfl][1] = *(const bf16x8*)&LB[B_][hb][offB[nq][nfl] ^ 32]; \
    } } while (0)
#define MMA_Q(mq, nq, bv) do { \
    _Pragma("unroll") \
    for (int ks = 0; ks < 2; ++ks) \
    _Pragma("unroll") \
    for (int mfl = 0; mfl < 4; ++mfl) \
    _Pragma("unroll") \
    for (int nfl = 0; nfl < 2; ++nfl) \
        acc[mq * 4 + mfl][nq * 2 + nfl] = __builtin_amdgcn_mfma_f32_16x16x32_bf16( \
            av[mfl][ks], bv[nfl][ks], acc[mq * 4 + mfl][nq * 2 + nfl], 0, 0, 0); \
    } while (0)
#define BAR  __builtin_amdgcn_s_barrier()
#define SCB  __builtin_amdgcn_sched_barrier(0)
#define LGKM0 do { asm volatile("s_waitcnt lgkmcnt(0)" ::: "memory"); SCB; } while (0)
#define PRIO1 __builtin_amdgcn_s_setprio(1)
#define PRIO0 __builtin_amdgcn_s_setprio(0)

    f32x4 acc[8][4];
#pragma unroll
    for (int i = 0; i < 8; ++i)
#pragma unroll
        for (int j = 0; j < 4; ++j) acc[i][j] = (f32x4){0.f, 0.f, 0.f, 0.f};

    STG_A(0, 0, 0); STG_A(1, 0, 0); STG_B(0, 0, 0); STG_B(1, 0, 0);
    STG_B(0, 1, 1); STG_B(1, 1, 1); STG_A(0, 1, 1);
    asm volatile("s_waitcnt vmcnt(6)" ::: "memory");
    SCB; BAR;

    for (int i = 0; i < NIT; ++i) {
        const int t0 = 2 * i, t1 = 2 * i + 1;
        const bool st = (i + 1 < NIT);
        bf16x8 av[4][2], bv0[2][2], bv1[2][2];

        LDA_SUB(0, 0); LDB_SUB(0, 0, bv0);
        STG_A(1, t1, 1);
        BAR; LGKM0;
        PRIO1; MMA_Q(0, 0, bv0); PRIO0;
        BAR;

        LDB_SUB(0, 1, bv1);
        BAR; LGKM0;
        PRIO1; MMA_Q(0, 1, bv1); PRIO0;
        BAR;

        LDA_SUB(0, 1);
        if (st) STG_B(0, t0 + 2, 0);
        BAR; LGKM0;
        PRIO1; MMA_Q(1, 1, bv1); PRIO0;
        BAR;

        if (st) { STG_B(1, t0 + 2, 0); STG_A(0, t0 + 2, 0); }
        BAR;
        PRIO1; MMA_Q(1, 0, bv0); PRIO0;
        if (st) asm volatile("s_waitcnt vmcnt(6)" ::: "memory");
        else    asm volatile("s_waitcnt vmcnt(0)" ::: "memory");
        SCB; BAR;

        LDA_SUB(1, 0); LDB_SUB(1, 0, bv0);
        if (st) STG_A(1, t0 + 2, 0);
        BAR; LGKM0;
        PRIO1; MMA_Q(0, 0, bv0); PRIO0;
        BAR;

        LDB_SUB(1, 1, bv1);
        BAR; LGKM0;
        PRIO1; MMA_Q(0, 1, bv1); PRIO0;
        BAR;

        LDA_SUB(1, 1);
        if (st) STG_B(0, t1 + 2, 1);
        BAR; LGKM0;
        PRIO1; MMA_Q(1, 1, bv1); PRIO0;
        BAR;

        if (st) { STG_B(1, t1 + 2, 1); STG_A(0, t1 + 2, 1); }
        BAR;
        PRIO1; MMA_Q(1, 0, bv0); PRIO0;
        if (st) asm volatile("s_waitcnt vmcnt(6)" ::: "memory");
        else    asm volatile("s_waitcnt vmcnt(0)" ::: "memory");
        SCB; BAR;
    }

#undef STG_A
#undef STG_B
#undef LDA_SUB
#undef LDB_SUB
#undef MMA_Q
#undef BAR
#undef SCB
#undef LGKM0
#undef PRIO1
#undef PRIO0

    const int wm = wr * 128, wn = wc * 64;
#pragma unroll
    for (int nf = 0; nf < 4; ++nf) {
        int col = (int)n0 + wn + nf * 16 + fr;
        float bs = (col < nsplit) ? bias0[col] : bias1[col - nsplit];
#pragma unroll
        for (int mf = 0; mf < 8; ++mf) {
            size_t rowb = m0 + wm + mf * 16 + fs * 4;
#pragma unroll
            for (int r = 0; r < 4; ++r) {
                float v = acc[mf][nf][r] + bs;
                if (OUTBF) ((unsigned short*)Cv)[(rowb + r) * N + col] = f2bf(v);
                else       ((float*)Cv)[(rowb + r) * N + col] = v;
            }
        }
    }
}

// ---------- fused per-b kernel: 768 threads (12 waves), 1 H-column per thread ----------
__global__ __launch_bounds__(768) void fused_kernel(
    const float* __restrict__ qf_g, const unsigned short* __restrict__ qbf,
    const unsigned short* __restrict__ qe_g, const unsigned short* __restrict__ imgCE,
    const unsigned short* __restrict__ imf_bf,
    const float* __restrict__ g1, const float* __restrict__ b1,
    const float* __restrict__ g2, const float* __restrict__ b2,
    const float* __restrict__ g3, const float* __restrict__ b3,
    const float* __restrict__ g4, const float* __restrict__ b4,
    const float* __restrict__ g5, const float* __restrict__ b5,
    const float* __restrict__ wqa, const float* __restrict__ bqa,
    const float* __restrict__ wia, const float* __restrict__ bia,
    float* __restrict__ out_i, float* __restrict__ out_q)
{
    const int b = blockIdx.x;
    const int tid = threadIdx.x, lane = tid & 63, wid = tid >> 6;   // wid 0..11
    __shared__ unsigned short buf[14 * 768];   // bf16: qbf (phase 1) then qe (phases 2-3)
    __shared__ float wms[14 * 100];
    __shared__ float red[12][28];
    __shared__ float mu_s[14], rs_s[14], qa_s[14], qw_s[14];
    __shared__ float mu2_s[10], rs2_s[10];
    __shared__ float ia_s[100], iw_s[100];

    // ===== phase 1: wm =====
    {
        const ushort8_t* src = (const ushort8_t*)(qbf + (size_t)b * 14 * 768);
        for (int i = tid; i < 14 * 768 / 8; i += 768) *(ushort8_t*)&buf[i * 8] = src[i];
    }
    __syncthreads();
    {
        float rcur[12], rnxt[12];
        {
            const unsigned short* row = imgCE + ((size_t)b * 100 + wid) * 1536;
#pragma unroll
            for (int j = 0; j < 12; ++j) rnxt[j] = bf2f(row[lane + 64 * j]);
        }
        for (int n = wid; n < 100; n += 12) {
#pragma unroll
            for (int j = 0; j < 12; ++j) rcur[j] = rnxt[j];
            if (n + 12 < 100) {
                const unsigned short* row = imgCE + ((size_t)b * 100 + n + 12) * 1536;
#pragma unroll
                for (int j = 0; j < 12; ++j) rnxt[j] = bf2f(row[lane + 64 * j]);
            }
            for (int t = 0; t < 14; ++t) {
                const unsigned short* q = buf + t * 768;
                float s = 0.f;
#pragma unroll
                for (int j = 0; j < 12; ++j) s = fmaf(rcur[j], bf2f(q[lane + 64 * j]), s);
                s = wave_sum(s);
                if (lane == 0) wms[t * 100 + n] = s;
            }
        }
    }
    __syncthreads();
    for (int t = wid; t < 14; t += 12) {
        float x0 = wms[t * 100 + lane];
        float x1 = (lane + 64 < 100) ? wms[t * 100 + lane + 64] : 0.f;
        float s = wave_sum(x0 + x1);
        float q = wave_sum(x0 * x0 + x1 * x1);
        float mu = s * (1.f / 100.f);
        float var = q * (1.f / 100.f) - mu * mu;
        float rs = rsqrtf(var + 1e-3f);
        {
            float v = (x0 - mu) * rs * g1[lane] + b1[lane];
            wms[t * 100 + lane] = v > 0.f ? v : 0.f;
        }
        if (lane + 64 < 100) {
            float v = (x1 - mu) * rs * g1[lane + 64] + b1[lane + 64];
            wms[t * 100 + lane + 64] = v > 0.f ? v : 0.f;
        }
    }
    // restage buf with qe (bf16 raw copy)
    {
        const ushort8_t* src = (const ushort8_t*)(qe_g + (size_t)b * 14 * 768);
        for (int i = tid; i < 14 * 768 / 8; i += 768) *(ushort8_t*)&buf[i * 8] = src[i];
    }
    __syncthreads();

    // ===== phase 2: ques path (1 column per thread) =====
    {
        float a[14];
#pragma unroll
        for (int t = 0; t < 14; ++t) a[t] = 0.f;

        const unsigned short* ie_base = imgCE + (size_t)b * 100 * 1536 + 768;  // img_embed
        float en = bf2f(ie_base[tid]);
        for (int n = 0; n < 100; ++n) {
            float e = en;
            if (n < 99) en = bf2f(ie_base[(size_t)(n + 1) * 1536 + tid]);
#pragma unroll
            for (int t = 0; t < 14; ++t)
                a[t] = fmaf(wms[t * 100 + n], e, a[t]);
        }
#pragma unroll
        for (int t = 0; t < 14; ++t) a[t] += bf2f(buf[t * 768 + tid]);

#pragma unroll
        for (int t = 0; t < 14; ++t) {
            float s = wave_sum(a[t]);
            float q = wave_sum(a[t] * a[t]);
            if (lane == 0) { red[wid][t] = s; red[wid][14 + t] = q; }
        }
        __syncthreads();
        if (tid < 14) {
            float s = 0.f, q = 0.f;
#pragma unroll
            for (int w = 0; w < 12; ++w) { s += red[w][tid]; q += red[w][14 + tid]; }
            float mu = s * (1.f / 768.f);
            float var = q * (1.f / 768.f) - mu * mu;
            mu_s[tid] = mu; rs_s[tid] = rsqrtf(var + 1e-3f);
        }
        __syncthreads();

        float ga = g2[tid], ba = b2[tid], w0 = wqa[tid];
#pragma unroll
        for (int t = 0; t < 14; ++t) {
            float mu = mu_s[t], rs = rs_s[t];
            float v = fmaxf((a[t] - mu) * rs * ga + ba, 0.f);
            float p = wave_sum(v * w0);
            if (lane == 0) red[wid][t] = p;
        }
        __syncthreads();
        if (tid < 14) {
            float p = 0.f;
#pragma unroll
            for (int w = 0; w < 12; ++w) p += red[w][tid];
            qa_s[tid] = p + bqa[0];
        }
        __syncthreads();
        if (tid == 0) {
            float s = 0.f;
            for (int t = 0; t < 14; ++t) s += qa_s[t];
            float mu = s * (1.f / 14.f);
            float q = 0.f;
            for (int t = 0; t < 14; ++t) { float d = qa_s[t] - mu; q += d * d; }
            float rs = rsqrtf(q * (1.f / 14.f) + 1e-3f);
            float e[14], mx = -1e30f;
            for (int t = 0; t < 14; ++t) { e[t] = (qa_s[t] - mu) * rs * g3[t] + b3[t]; mx = fmaxf(mx, e[t]); }
            float se = 0.f;
            for (int t = 0; t < 14; ++t) { e[t] = expf(e[t] - mx); se += e[t]; }
            float inv = 1.f / se;
            for (int t = 0; t < 14; ++t) qw_s[t] = e[t] * inv;
        }
        __syncthreads();

        const float* qf = qf_g + (size_t)b * 14 * 768;
        float o = 0.f;
#pragma unroll
        for (int t = 0; t < 14; ++t) o = fmaf(qw_s[t], qf[t * 768 + tid], o);
        out_q[(size_t)b * 768 + tid] = o;
    }
    __syncthreads();

    // ===== phase 3: img path (1 column per thread) =====
    {
        float g4a = g4[tid], b4a = b4[tid], wa = wia[tid];

        for (int g = 0; g < 10; ++g) {
            float ge[10];
#pragma unroll
            for (int i = 0; i < 10; ++i)
                ge[i] = bf2f(imgCE[((size_t)b * 100 + g * 10 + i) * 1536 + 768 + tid]);
            float t0[10];
#pragma unroll
            for (int i = 0; i < 10; ++i) t0[i] = 0.f;
#pragma unroll
            for (int t = 0; t < 14; ++t) {
                float q0 = bf2f(buf[t * 768 + tid]);
#pragma unroll
                for (int i = 0; i < 10; ++i)
                    t0[i] = fmaf(wms[t * 100 + g * 10 + i], q0, t0[i]);
            }
#pragma unroll
            for (int i = 0; i < 10; ++i) {
                t0[i] += ge[i];
                float s = wave_sum(t0[i]);
                float q = wave_sum(t0[i] * t0[i]);
                if (lane == 0) { red[wid][i] = s; red[wid][10 + i] = q; }
            }
            __syncthreads();
            if (tid < 10) {
                float s = 0.f, q = 0.f;
#pragma unroll
                for (int w = 0; w < 12; ++w) { s += red[w][tid]; q += red[w][10 + tid]; }
                float mu = s * (1.f / 768.f);
                float var = q * (1.f / 768.f) - mu * mu;
                mu2_s[tid] = mu; rs2_s[tid] = rsqrtf(var + 1e-3f);
            }
            __syncthreads();
#pragma unroll
            for (int i = 0; i < 10; ++i) {
                float mu = mu2_s[i], rs = rs2_s[i];
                float v = fmaxf((t0[i] - mu) * rs * g4a + b4a, 0.f);
                float p = wave_sum(v * wa);
                if (lane == 0) red[wid][i] = p;
            }
            __syncthreads();
            if (tid < 10) {
                float p = 0.f;
#pragma unroll
                for (int w = 0; w < 12; ++w) p += red[w][tid];
                ia_s[g * 10 + tid] = p + bia[0];
            }
            __syncthreads();
        }

        if (wid == 0) {
            float x0 = ia_s[lane];
            float x1 = (lane + 64 < 100) ? ia_s[lane + 64] : 0.f;
            float s = wave_sum(x0 + x1);
            float q = wave_sum(x0 * x0 + x1 * x1);
            float mu = s * 0.01f;
            float var = q * 0.01f - mu * mu;
            float rs = rsqrtf(var + 1e-3f);
            float v0 = (x0 - mu) * rs * g5[lane] + b5[lane];
            float v1 = (lane + 64 < 100) ? (x1 - mu) * rs * g5[lane + 64] + b5[lane + 64] : -1e30f;
            float mx = wave_max(fmaxf(v0, v1));
            float e0 = expf(v0 - mx);
            float e1 = (lane + 64 < 100) ? expf(v1 - mx) : 0.f;
            float se = wave_sum(e0 + e1);
            float inv = 1.f / se;
            iw_s[lane] = e0 * inv;
            if (lane + 64 < 100) iw_s[lane + 64] = e1 * inv;
        }
        __syncthreads();

        // img_atten_feat: 512 threads x 4 cols (ushort4 loads)
        if (tid < 512) {
            const unsigned short* imf = imf_bf + (size_t)b * 100 * 2048;
            float acc4[4] = {0.f, 0.f, 0.f, 0.f};
            for (int n = 0; n < 100; ++n) {
                ushort4_t v = *(const ushort4_t*)(imf + (size_t)n * 2048 + tid * 4);
                float w = iw_s[n];
#pragma unroll
                for (int j = 0; j < 4; ++j) acc4[j] = fmaf(w, bf2f(v[j]), acc4[j]);
            }
            float4 o = {acc4[0], acc4[1], acc4[2], acc4[3]};
            ((float4*)(out_i + (size_t)b * 2048))[tid] = o;
        }
    }
}

// ---------- launch ----------
extern "C" void kernel_launch(void* const* d_in, const int* in_sizes, int n_in,
                              void* d_out, int out_size, void* d_ws, size_t ws_size,
                              hipStream_t stream)
{
    const float* img_feat = (const float*)d_in[0];
    const float* ques_feat = (const float*)d_in[1];
    const float* Wc = (const float*)d_in[2];
    const float* bc = (const float*)d_in[3];
    const float* Wq = (const float*)d_in[4];
    const float* bq = (const float*)d_in[5];
    const float* Wi = (const float*)d_in[6];
    const float* bi = (const float*)d_in[7];
    const float* wqa = (const float*)d_in[8];
    const float* bqa = (const float*)d_in[9];
    const float* wia = (const float*)d_in[10];
    const float* bia = (const float*)d_in[11];
    const float* g1 = (const float*)d_in[12]; const float* b1 = (const float*)d_in[13];
    const float* g2 = (const float*)d_in[14]; const float* b2 = (const float*)d_in[15];
    const float* g3 = (const float*)d_in[16]; const float* b3 = (const float*)d_in[17];
    const float* g4 = (const float*)d_in[18]; const float* b4 = (const float*)d_in[19];
    const float* g5 = (const float*)d_in[20]; const float* b5 = (const float*)d_in[21];

    // workspace layout (bytes)
    const size_t SZ_WP   = 1536u * 2048u * 2u;
    const size_t SZ_WQT  = 768u * 768u * 2u;
    const size_t SZ_IMG  = 51200ull * 1536u * 2u;     // bf16
    const size_t SZ_QE   = 7168u * 768u * 4u;
    const size_t SZ_WM   = 512u * 1400u * 4u;
    const size_t SZ_ABF  = 51200ull * 2048u * 2u;
    const size_t SZ_QBF  = 7168u * 768u * 2u;

    const size_t OFF_WP  = 0;
    const size_t OFF_WQT = OFF_WP + SZ_WP;
    const size_t OFF_IMG = OFF_WQT + SZ_WQT;
    const size_t OFF_QE  = OFF_IMG + SZ_IMG;
    const size_t OFF_WM  = OFF_QE + SZ_QE;
    const size_t OFF_ABF = OFF_WM + SZ_WM;
    const size_t OFF_QBF = OFF_ABF + SZ_ABF;
    const size_t NEED    = OFF_QBF + SZ_QBF;
    if (ws_size < NEED) return;

    char* ws = (char*)d_ws;
    unsigned short* Wp    = (unsigned short*)(ws + OFF_WP);
    unsigned short* Wqt   = (unsigned short*)(ws + OFF_WQT);
    unsigned short* imgCE = (unsigned short*)(ws + OFF_IMG);
    unsigned short* qe    = (unsigned short*)(ws + OFF_QE);
    unsigned short* Abf   = (unsigned short*)(ws + OFF_ABF);
    unsigned short* Qbf   = (unsigned short*)(ws + OFF_QBF);

    float* out_img = (float*)d_out;                   // [512][2048]
    float* out_q   = (float*)d_out + 512 * 2048;      // [512][768]

    hipLaunchKernelGGL(pack_t, dim3(32, 24), dim3(256), 0, stream, Wc, Wi, 768, Wp, 2048);
    hipLaunchKernelGGL(pack_t, dim3(12, 12), dim3(256), 0, stream, Wq, Wq, 768, Wqt, 768);
    hipLaunchKernelGGL(cvt2, dim3(2304), dim3(256), 0, stream,
                       img_feat, Abf, (long)(51200ull * 2048u / 8u),
                       ques_feat, Qbf, (long)(7168u * 768u / 8u), 2048);

    // imgCE(bf16) = img_feat @ [Wc|Wi] + [bc|bi]   (M=51200, N=1536, K=2048)
    hipLaunchKernelGGL(HIP_KERNEL_NAME(gemm8<1>), dim3(1200), dim3(512), 0, stream,
                       Abf, Wp, bc, bi, 768, (void*)imgCE, 1536, 2048, 6);
    // qe(bf16) = ques_feat @ Wq + bq               (M=7168, N=768, K=768)
    hipLaunchKernelGGL(HIP_KERNEL_NAME(gemm8<1>), dim3(84), dim3(512), 0, stream,
                       Qbf, Wqt, bq, bq, 768, (void*)qe, 768, 768, 3);

    hipLaunchKernelGGL(fused_kernel, dim3(512), dim3(768), 0, stream,
                       ques_feat, Qbf, qe, imgCE, Abf,
                       g1, b1, g2, b2, g3, b3, g4, b4, g5, b5,
                       wqa, bqa, wia, bia, out_img, out_q);
}

// Round 12
// 937.443 us; speedup vs baseline: 1.1016x; 1.1016x over previous
//
#include <hip/hip_runtime.h>

// ---------- types & helpers ----------
using f32x4     = __attribute__((ext_vector_type(4))) float;
using bf16x8    = __attribute__((ext_vector_type(8))) short;
using ushort4_t = __attribute__((ext_vector_type(4))) unsigned short;
using ushort8_t = __attribute__((ext_vector_type(8))) unsigned short;

__device__ __forceinline__ unsigned short f2bf(float f) {
    unsigned u = __builtin_bit_cast(unsigned, f);
    u += 0x7fffu + ((u >> 16) & 1u);   // RNE
    return (unsigned short)(u >> 16);
}
__device__ __forceinline__ float bf2f(unsigned short h) {
    return __builtin_bit_cast(float, (unsigned)h << 16);
}

__device__ __forceinline__ float wave_sum(float v) {
#pragma unroll
    for (int off = 32; off > 0; off >>= 1) v += __shfl_xor(v, off, 64);
    return v;
}
__device__ __forceinline__ float wave_max(float v) {
#pragma unroll
    for (int off = 32; off > 0; off >>= 1) v = fmaxf(v, __shfl_xor(v, off, 64));
    return v;
}

#define GLP(p)  ((const __attribute__((address_space(1))) void*)(p))
#define LDSP(p) ((__attribute__((address_space(3))) void*)(p))

// ---------- dual f32 -> bf16 bulk convert (two jobs, one launch) ----------
__global__ __launch_bounds__(256) void cvt2(
    const float* __restrict__ in0, unsigned short* __restrict__ out0, long n80,
    const float* __restrict__ in1, unsigned short* __restrict__ out1, long n81, int split)
{
    const float* in; unsigned short* out; long n8, i, stride;
    if ((int)blockIdx.x < split) {
        in = in0; out = out0; n8 = n80;
        i = (long)blockIdx.x * 256 + threadIdx.x; stride = (long)split * 256;
    } else {
        in = in1; out = out1; n8 = n81;
        i = (long)(blockIdx.x - split) * 256 + threadIdx.x;
        stride = (long)(gridDim.x - split) * 256;
    }
    for (; i < n8; i += stride) {
        const float4* p = (const float4*)(in + i * 8);
        float4 a = p[0], b = p[1];
        ushort8_t v;
        v[0] = f2bf(a.x); v[1] = f2bf(a.y); v[2] = f2bf(a.z); v[3] = f2bf(a.w);
        v[4] = f2bf(b.x); v[5] = f2bf(b.y); v[6] = f2bf(b.z); v[7] = f2bf(b.w);
        *(ushort8_t*)(out + i * 8) = v;
    }
}

// ---------- coalesced LDS-tiled weight transpose -> bf16 [N][K] ----------
__global__ __launch_bounds__(256) void pack_t(
    const float* __restrict__ S0, const float* __restrict__ S1, int nsplit,
    unsigned short* __restrict__ D, int K)
{
    __shared__ float t[64][65];
    const int k0 = blockIdx.x * 64, n0 = blockIdx.y * 64;
    const float* S = (n0 < nsplit) ? S0 : S1;
    const int nb = (n0 < nsplit) ? n0 : n0 - nsplit;
    const int c = threadIdx.x & 63, r4 = threadIdx.x >> 6;
#pragma unroll
    for (int it = 0; it < 16; ++it) {
        int r = it * 4 + r4;
        t[r][c] = S[(size_t)(k0 + r) * nsplit + nb + c];
    }
    __syncthreads();
#pragma unroll
    for (int it = 0; it < 16; ++it) {
        int rn = it * 4 + r4;
        D[(size_t)(n0 + rn) * K + k0 + c] = f2bf(t[c][rn]);
    }
}

// ---------- 256x256 bf16 GEMM, 8-phase (FROZEN, R7/R8 config) ----------
template <int OUTBF>
__global__ __launch_bounds__(512, 1) void gemm8(
    const unsigned short* __restrict__ A, const unsigned short* __restrict__ Bt,
    const float* __restrict__ bias0, const float* __restrict__ bias1, int nsplit,
    void* __restrict__ Cv, int N, int K, int NTN)
{
    __shared__ unsigned short LA[2][2][8192];
    __shared__ unsigned short LB[2][2][8192];
    const int tid = threadIdx.x, lane = tid & 63, wid = tid >> 6;

    int nwg = (int)gridDim.x, bid = (int)blockIdx.x;
    if ((nwg & 7) == 0) { int cpx = nwg >> 3; bid = (bid & 7) * cpx + (bid >> 3); }  // T1
    const int tn = bid % NTN, tm = bid / NTN;
    const size_t m0 = (size_t)tm * 256, n0 = (size_t)tn * 256;
    const int NT = K >> 6;
    const int NIT = NT >> 1;

    const int wr = wid >> 2, wc = wid & 3;
    const int hb = wc >> 1;
    const int fr = lane & 15, fs = lane >> 4;

    const int r0 = tid >> 3, s0 = ((tid & 7) - r0) & 7;
    const int r1 = r0 + 64,  s1 = ((tid & 7) - r1) & 7;
    const unsigned short* pA[2][2];
    const unsigned short* pB[2][2];
#pragma unroll
    for (int h = 0; h < 2; ++h) {
        pA[h][0] = A  + (m0 + h * 128 + r0) * K + s0 * 8;
        pA[h][1] = A  + (m0 + h * 128 + r1) * K + s1 * 8;
        pB[h][0] = Bt + (n0 + h * 128 + r0) * K + s0 * 8;
        pB[h][1] = Bt + (n0 + h * 128 + r1) * K + s1 * 8;
    }
    const int d0 = tid * 8, d1 = (tid + 512) * 8;

#define STG_A(h, t, B_) do { \
    __builtin_amdgcn_global_load_lds(GLP(pA[h][0] + (size_t)(t) * 64), LDSP(&LA[B_][h][d0]), 16, 0, 0); \
    __builtin_amdgcn_global_load_lds(GLP(pA[h][1] + (size_t)(t) * 64), LDSP(&LA[B_][h][d1]), 16, 0, 0); \
} while (0)
#define STG_B(h, t, B_) do { \
    __builtin_amdgcn_global_load_lds(GLP(pB[h][0] + (size_t)(t) * 64), LDSP(&LB[B_][h][d0]), 16, 0, 0); \
    __builtin_amdgcn_global_load_lds(GLP(pB[h][1] + (size_t)(t) * 64), LDSP(&LB[B_][h][d1]), 16, 0, 0); \
} while (0)

    int offA[2][4], offB[2][2];
#pragma unroll
    for (int mq = 0; mq < 2; ++mq)
#pragma unroll
        for (int mfl = 0; mfl < 4; ++mfl) {
            int r = mq * 64 + mfl * 16 + fr;
            offA[mq][mfl] = r * 64 + ((fs + r) & 7) * 8;
        }
#pragma unroll
    for (int nq = 0; nq < 2; ++nq)
#pragma unroll
        for (int nfl = 0; nfl < 2; ++nfl) {
            int r = (wc & 1) * 64 + nq * 32 + nfl * 16 + fr;
            offB[nq][nfl] = r * 64 + ((fs + r) & 7) * 8;
        }

#define LDA_SUB(B_, mq) do { \
    _Pragma("unroll") \
    for (int mfl = 0; mfl < 4; ++mfl) { \
        av[mfl][0] = *(const bf16x8*)&LA[B_][wr][offA[mq][mfl]]; \
        av[mfl][1] = *(const bf16x8*)&LA[B_][wr][offA[mq][mfl] ^ 32]; \
    } } while (0)
#define LDB_SUB(B_, nq, bv) do { \
    _Pragma("unroll") \
    for (int nfl = 0; nfl < 2; ++nfl) { \
        bv[nfl][0] = *(const bf16x8*)&LB[B_][hb][offB[nq][nfl]]; \
        bv[nfl][1] = *(const bf16x8*)&LB[B_][hb][offB[nq][nfl] ^ 32]; \
    } } while (0)
#define MMA_Q(mq, nq, bv) do { \
    _Pragma("unroll") \
    for (int ks = 0; ks < 2; ++ks) \
    _Pragma("unroll") \
    for (int mfl = 0; mfl < 4; ++mfl) \
    _Pragma("unroll") \
    for (int nfl = 0; nfl < 2; ++nfl) \
        acc[mq * 4 + mfl][nq * 2 + nfl] = __builtin_amdgcn_mfma_f32_16x16x32_bf16( \
            av[mfl][ks], bv[nfl][ks], acc[mq * 4 + mfl][nq * 2 + nfl], 0, 0, 0); \
    } while (0)
#define BAR  __builtin_amdgcn_s_barrier()
#define SCB  __builtin_amdgcn_sched_barrier(0)
#define LGKM0 do { asm volatile("s_waitcnt lgkmcnt(0)" ::: "memory"); SCB; } while (0)
#define PRIO1 __builtin_amdgcn_s_setprio(1)
#define PRIO0 __builtin_amdgcn_s_setprio(0)

    f32x4 acc[8][4];
#pragma unroll
    for (int i = 0; i < 8; ++i)
#pragma unroll
        for (int j = 0; j < 4; ++j) acc[i][j] = (f32x4){0.f, 0.f, 0.f, 0.f};

    STG_A(0, 0, 0); STG_A(1, 0, 0); STG_B(0, 0, 0); STG_B(1, 0, 0);
    STG_B(0, 1, 1); STG_B(1, 1, 1); STG_A(0, 1, 1);
    asm volatile("s_waitcnt vmcnt(6)" ::: "memory");
    SCB; BAR;

    for (int i = 0; i < NIT; ++i) {
        const int t0 = 2 * i, t1 = 2 * i + 1;
        const bool st = (i + 1 < NIT);
        bf16x8 av[4][2], bv0[2][2], bv1[2][2];

        LDA_SUB(0, 0); LDB_SUB(0, 0, bv0);
        STG_A(1, t1, 1);
        BAR; LGKM0;
        PRIO1; MMA_Q(0, 0, bv0); PRIO0;
        BAR;

        LDB_SUB(0, 1, bv1);
        BAR; LGKM0;
        PRIO1; MMA_Q(0, 1, bv1); PRIO0;
        BAR;

        LDA_SUB(0, 1);
        if (st) STG_B(0, t0 + 2, 0);
        BAR; LGKM0;
        PRIO1; MMA_Q(1, 1, bv1); PRIO0;
        BAR;

        if (st) { STG_B(1, t0 + 2, 0); STG_A(0, t0 + 2, 0); }
        BAR;
        PRIO1; MMA_Q(1, 0, bv0); PRIO0;
        if (st) asm volatile("s_waitcnt vmcnt(6)" ::: "memory");
        else    asm volatile("s_waitcnt vmcnt(0)" ::: "memory");
        SCB; BAR;

        LDA_SUB(1, 0); LDB_SUB(1, 0, bv0);
        if (st) STG_A(1, t0 + 2, 0);
        BAR; LGKM0;
        PRIO1; MMA_Q(0, 0, bv0); PRIO0;
        BAR;

        LDB_SUB(1, 1, bv1);
        BAR; LGKM0;
        PRIO1; MMA_Q(0, 1, bv1); PRIO0;
        BAR;

        LDA_SUB(1, 1);
        if (st) STG_B(0, t1 + 2, 1);
        BAR; LGKM0;
        PRIO1; MMA_Q(1, 1, bv1); PRIO0;
        BAR;

        if (st) { STG_B(1, t1 + 2, 1); STG_A(0, t1 + 2, 1); }
        BAR;
        PRIO1; MMA_Q(1, 0, bv0); PRIO0;
        if (st) asm volatile("s_waitcnt vmcnt(6)" ::: "memory");
        else    asm volatile("s_waitcnt vmcnt(0)" ::: "memory");
        SCB; BAR;
    }

#undef STG_A
#undef STG_B
#undef LDA_SUB
#undef LDB_SUB
#undef MMA_Q
#undef BAR
#undef SCB
#undef LGKM0
#undef PRIO1
#undef PRIO0

    const int wm = wr * 128, wn = wc * 64;
#pragma unroll
    for (int nf = 0; nf < 4; ++nf) {
        int col = (int)n0 + wn + nf * 16 + fr;
        float bs = (col < nsplit) ? bias0[col] : bias1[col - nsplit];
#pragma unroll
        for (int mf = 0; mf < 8; ++mf) {
            size_t rowb = m0 + wm + mf * 16 + fs * 4;
#pragma unroll
            for (int r = 0; r < 4; ++r) {
                float v = acc[mf][nf][r] + bs;
                if (OUTBF) ((unsigned short*)Cv)[(rowb + r) * N + col] = f2bf(v);
                else       ((float*)Cv)[(rowb + r) * N + col] = v;
            }
        }
    }
}

// ---------- fused per-b kernel: 256 threads, vectorized streams ----------
// phase1: lane owns 12 contiguous cols (ushort4 x3 loads).
// phase2/3: threads 0..191 own 4 contiguous cols (ushort4/float4); wave3 idle in col work,
// participates in reductions with zero partials. Reduction structure identical to R10.
__global__ __launch_bounds__(256) void fused_kernel(
    const float* __restrict__ qf_g, const unsigned short* __restrict__ qbf,
    const unsigned short* __restrict__ qe_g, const unsigned short* __restrict__ imgCE,
    const unsigned short* __restrict__ imf_bf,
    const float* __restrict__ g1, const float* __restrict__ b1,
    const float* __restrict__ g2, const float* __restrict__ b2,
    const float* __restrict__ g3, const float* __restrict__ b3,
    const float* __restrict__ g4, const float* __restrict__ b4,
    const float* __restrict__ g5, const float* __restrict__ b5,
    const float* __restrict__ wqa, const float* __restrict__ bqa,
    const float* __restrict__ wia, const float* __restrict__ bia,
    float* __restrict__ out_i, float* __restrict__ out_q)
{
    const int b = blockIdx.x;
    const int tid = threadIdx.x, lane = tid & 63, wid = tid >> 6;
    __shared__ unsigned short buf[14 * 768];   // bf16: qbf (phase 1) then qe (phases 2-3)
    __shared__ float wms[14 * 100];
    __shared__ float red[4][28];
    __shared__ float mu_s[14], rs_s[14], qa_s[14], qw_s[14];
    __shared__ float mu2_s[10], rs2_s[10];
    __shared__ float ia_s[100], iw_s[100];

    // ===== phase 1: wm =====
    {
        const ushort8_t* src = (const ushort8_t*)(qbf + (size_t)b * 14 * 768);
        for (int i = tid; i < 14 * 768 / 8; i += 256) *(ushort8_t*)&buf[i * 8] = src[i];
    }
    __syncthreads();
    {
        const unsigned short* rb = imgCE + (size_t)b * 100 * 1536 + 12 * lane;  // img_corr half
        ushort4_t rn0, rn1, rn2;
        {
            const unsigned short* r = rb + (size_t)wid * 1536;
            rn0 = *(const ushort4_t*)(r); rn1 = *(const ushort4_t*)(r + 4); rn2 = *(const ushort4_t*)(r + 8);
        }
        for (int n = wid; n < 100; n += 4) {
            float rc[12];
#pragma unroll
            for (int j = 0; j < 4; ++j) { rc[j] = bf2f(rn0[j]); rc[4 + j] = bf2f(rn1[j]); rc[8 + j] = bf2f(rn2[j]); }
            if (n + 4 < 100) {
                const unsigned short* r = rb + (size_t)(n + 4) * 1536;
                rn0 = *(const ushort4_t*)(r); rn1 = *(const ushort4_t*)(r + 4); rn2 = *(const ushort4_t*)(r + 8);
            }
            for (int t = 0; t < 14; ++t) {
                const unsigned short* q = buf + t * 768 + 12 * lane;
                ushort4_t q0 = *(const ushort4_t*)(q), q1 = *(const ushort4_t*)(q + 4), q2 = *(const ushort4_t*)(q + 8);
                float s = 0.f;
#pragma unroll
                for (int j = 0; j < 4; ++j) s = fmaf(rc[j], bf2f(q0[j]), s);
#pragma unroll
                for (int j = 0; j < 4; ++j) s = fmaf(rc[4 + j], bf2f(q1[j]), s);
#pragma unroll
                for (int j = 0; j < 4; ++j) s = fmaf(rc[8 + j], bf2f(q2[j]), s);
                s = wave_sum(s);
                if (lane == 0) wms[t * 100 + n] = s;
            }
        }
    }
    __syncthreads();
    for (int t = wid; t < 14; t += 4) {
        float x0 = wms[t * 100 + lane];
        float x1 = (lane + 64 < 100) ? wms[t * 100 + lane + 64] : 0.f;
        float s = wave_sum(x0 + x1);
        float q = wave_sum(x0 * x0 + x1 * x1);
        float mu = s * (1.f / 100.f);
        float var = q * (1.f / 100.f) - mu * mu;
        float rs = rsqrtf(var + 1e-3f);
        {
            float v = (x0 - mu) * rs * g1[lane] + b1[lane];
            wms[t * 100 + lane] = v > 0.f ? v : 0.f;
        }
        if (lane + 64 < 100) {
            float v = (x1 - mu) * rs * g1[lane + 64] + b1[lane + 64];
            wms[t * 100 + lane + 64] = v > 0.f ? v : 0.f;
        }
    }
    // restage buf with qe (bf16 raw copy)
    {
        const ushort8_t* src = (const ushort8_t*)(qe_g + (size_t)b * 14 * 768);
        for (int i = tid; i < 14 * 768 / 8; i += 256) *(ushort8_t*)&buf[i * 8] = src[i];
    }
    __syncthreads();

    const bool act = tid < 192;
    const int c0 = tid * 4;

    // ===== phase 2: ques path (4 contiguous cols per active thread) =====
    {
        float a[14][4];
#pragma unroll
        for (int t = 0; t < 14; ++t)
#pragma unroll
            for (int j = 0; j < 4; ++j) a[t][j] = 0.f;

        const unsigned short* ie0 = imgCE + (size_t)b * 100 * 1536 + 768 + c0;  // img_embed
        ushort4_t er0, er1, er2, er3;
        if (act) {
            er0 = *(const ushort4_t*)(ie0);
            er1 = *(const ushort4_t*)(ie0 + 1536);
            er2 = *(const ushort4_t*)(ie0 + 2 * 1536);
            er3 = *(const ushort4_t*)(ie0 + 3 * 1536);
        }
#define P2STEP(n_, er_) do { \
    float ef[4] = {bf2f(er_[0]), bf2f(er_[1]), bf2f(er_[2]), bf2f(er_[3])}; \
    if ((n_) + 4 < 100) er_ = *(const ushort4_t*)(ie0 + (size_t)((n_) + 4) * 1536); \
    _Pragma("unroll") \
    for (int t = 0; t < 14; ++t) { \
        float w = wms[t * 100 + (n_)]; \
        _Pragma("unroll") \
        for (int j = 0; j < 4; ++j) a[t][j] = fmaf(w, ef[j], a[t][j]); \
    } } while (0)
        for (int n4 = 0; n4 < 100; n4 += 4) {
            if (act) {
                P2STEP(n4 + 0, er0);
                P2STEP(n4 + 1, er1);
                P2STEP(n4 + 2, er2);
                P2STEP(n4 + 3, er3);
            }
        }
#undef P2STEP
        if (act) {
#pragma unroll
            for (int t = 0; t < 14; ++t) {
                ushort4_t qv = *(const ushort4_t*)&buf[t * 768 + c0];
#pragma unroll
                for (int j = 0; j < 4; ++j) a[t][j] += bf2f(qv[j]);
            }
        }
#pragma unroll
        for (int t = 0; t < 14; ++t) {
            float sp = 0.f, qp = 0.f;
            if (act) {
#pragma unroll
                for (int j = 0; j < 4; ++j) { sp += a[t][j]; qp += a[t][j] * a[t][j]; }
            }
            float s = wave_sum(sp);
            float q = wave_sum(qp);
            if (lane == 0) { red[wid][t] = s; red[wid][14 + t] = q; }
        }
        __syncthreads();
        if (tid < 14) {
            float s = red[0][tid] + red[1][tid] + red[2][tid] + red[3][tid];
            float q = red[0][14 + tid] + red[1][14 + tid] + red[2][14 + tid] + red[3][14 + tid];
            float mu = s * (1.f / 768.f);
            float var = q * (1.f / 768.f) - mu * mu;
            mu_s[tid] = mu; rs_s[tid] = rsqrtf(var + 1e-3f);
        }
        __syncthreads();

        f32x4 ga, ba, wq;
        if (act) {
            ga = *(const f32x4*)(g2 + c0); ba = *(const f32x4*)(b2 + c0); wq = *(const f32x4*)(wqa + c0);
        }
#pragma unroll
        for (int t = 0; t < 14; ++t) {
            float p = 0.f;
            if (act) {
                float mu = mu_s[t], rs = rs_s[t];
#pragma unroll
                for (int j = 0; j < 4; ++j) {
                    float v = fmaxf((a[t][j] - mu) * rs * ga[j] + ba[j], 0.f);
                    p = fmaf(v, wq[j], p);
                }
            }
            p = wave_sum(p);
            if (lane == 0) red[wid][t] = p;
        }
        __syncthreads();
        if (tid < 14) qa_s[tid] = red[0][tid] + red[1][tid] + red[2][tid] + red[3][tid] + bqa[0];
        __syncthreads();
        if (tid == 0) {
            float s = 0.f;
            for (int t = 0; t < 14; ++t) s += qa_s[t];
            float mu = s * (1.f / 14.f);
            float q = 0.f;
            for (int t = 0; t < 14; ++t) { float d = qa_s[t] - mu; q += d * d; }
            float rs = rsqrtf(q * (1.f / 14.f) + 1e-3f);
            float e[14], mx = -1e30f;
            for (int t = 0; t < 14; ++t) { e[t] = (qa_s[t] - mu) * rs * g3[t] + b3[t]; mx = fmaxf(mx, e[t]); }
            float se = 0.f;
            for (int t = 0; t < 14; ++t) { e[t] = expf(e[t] - mx); se += e[t]; }
            float inv = 1.f / se;
            for (int t = 0; t < 14; ++t) qw_s[t] = e[t] * inv;
        }
        __syncthreads();

        if (act) {
            const float* qf = qf_g + (size_t)b * 14 * 768 + c0;
            f32x4 o = {0.f, 0.f, 0.f, 0.f};
#pragma unroll
            for (int t = 0; t < 14; ++t) {
                f32x4 qv = *(const f32x4*)(qf + t * 768);
                float w = qw_s[t];
#pragma unroll
                for (int j = 0; j < 4; ++j) o[j] = fmaf(w, qv[j], o[j]);
            }
            *(f32x4*)(out_q + (size_t)b * 768 + c0) = o;
        }
    }
    __syncthreads();

    // ===== phase 3: img path (4 contiguous cols per active thread) =====
    {
        f32x4 g4v, b4v, wiv;
        if (act) {
            g4v = *(const f32x4*)(g4 + c0); b4v = *(const f32x4*)(b4 + c0); wiv = *(const f32x4*)(wia + c0);
        }
        for (int g = 0; g < 10; ++g) {
            ushort4_t gev[10];
            if (act) {
#pragma unroll
                for (int i = 0; i < 10; ++i)
                    gev[i] = *(const ushort4_t*)&imgCE[((size_t)b * 100 + g * 10 + i) * 1536 + 768 + c0];
            }
            float t0[10][4];
#pragma unroll
            for (int i = 0; i < 10; ++i)
#pragma unroll
                for (int j = 0; j < 4; ++j) t0[i][j] = 0.f;
            if (act) {
#pragma unroll
                for (int t = 0; t < 14; ++t) {
                    ushort4_t qv = *(const ushort4_t*)&buf[t * 768 + c0];
                    float qf4[4] = {bf2f(qv[0]), bf2f(qv[1]), bf2f(qv[2]), bf2f(qv[3])};
#pragma unroll
                    for (int i = 0; i < 10; ++i) {
                        float w = wms[t * 100 + g * 10 + i];
#pragma unroll
                        for (int j = 0; j < 4; ++j) t0[i][j] = fmaf(w, qf4[j], t0[i][j]);
                    }
                }
            }
#pragma unroll
            for (int i = 0; i < 10; ++i) {
                float sp = 0.f, qp = 0.f;
                if (act) {
#pragma unroll
                    for (int j = 0; j < 4; ++j) {
                        t0[i][j] += bf2f(gev[i][j]);
                        sp += t0[i][j]; qp += t0[i][j] * t0[i][j];
                    }
                }
                float s = wave_sum(sp);
                float q = wave_sum(qp);
                if (lane == 0) { red[wid][i] = s; red[wid][10 + i] = q; }
            }
            __syncthreads();
            if (tid < 10) {
                float s = red[0][tid] + red[1][tid] + red[2][tid] + red[3][tid];
                float q = red[0][10 + tid] + red[1][10 + tid] + red[2][10 + tid] + red[3][10 + tid];
                float mu = s * (1.f / 768.f);
                float var = q * (1.f / 768.f) - mu * mu;
                mu2_s[tid] = mu; rs2_s[tid] = rsqrtf(var + 1e-3f);
            }
            __syncthreads();
#pragma unroll
            for (int i = 0; i < 10; ++i) {
                float p = 0.f;
                if (act) {
                    float mu = mu2_s[i], rs = rs2_s[i];
#pragma unroll
                    for (int j = 0; j < 4; ++j) {
                        float v = fmaxf((t0[i][j] - mu) * rs * g4v[j] + b4v[j], 0.f);
                        p = fmaf(v, wiv[j], p);
                    }
                }
                p = wave_sum(p);
                if (lane == 0) red[wid][i] = p;
            }
            __syncthreads();
            if (tid < 10) ia_s[g * 10 + tid] = red[0][tid] + red[1][tid] + red[2][tid] + red[3][tid] + bia[0];
            __syncthreads();
        }

        if (wid == 0) {
            float x0 = ia_s[lane];
            float x1 = (lane + 64 < 100) ? ia_s[lane + 64] : 0.f;
            float s = wave_sum(x0 + x1);
            float q = wave_sum(x0 * x0 + x1 * x1);
            float mu = s * 0.01f;
            float var = q * 0.01f - mu * mu;
            float rs = rsqrtf(var + 1e-3f);
            float v0 = (x0 - mu) * rs * g5[lane] + b5[lane];
            float v1 = (lane + 64 < 100) ? (x1 - mu) * rs * g5[lane + 64] + b5[lane + 64] : -1e30f;
            float mx = wave_max(fmaxf(v0, v1));
            float e0 = expf(v0 - mx);
            float e1 = (lane + 64 < 100) ? expf(v1 - mx) : 0.f;
            float se = wave_sum(e0 + e1);
            float inv = 1.f / se;
            iw_s[lane] = e0 * inv;
            if (lane + 64 < 100) iw_s[lane + 64] = e1 * inv;
        }
        __syncthreads();

        const unsigned short* imf = imf_bf + (size_t)b * 100 * 2048;
        float acc8[8];
#pragma unroll
        for (int j = 0; j < 8; ++j) acc8[j] = 0.f;
        for (int n = 0; n < 100; ++n) {
            ushort8_t v = *(const ushort8_t*)(imf + (size_t)n * 2048 + tid * 8);
            float w = iw_s[n];
#pragma unroll
            for (int j = 0; j < 8; ++j) acc8[j] = fmaf(w, bf2f(v[j]), acc8[j]);
        }
        float4* dst = (float4*)(out_i + (size_t)b * 2048);
        float4 oA = {acc8[0], acc8[1], acc8[2], acc8[3]};
        float4 oB = {acc8[4], acc8[5], acc8[6], acc8[7]};
        dst[tid * 2] = oA; dst[tid * 2 + 1] = oB;
    }
}

// ---------- launch ----------
extern "C" void kernel_launch(void* const* d_in, const int* in_sizes, int n_in,
                              void* d_out, int out_size, void* d_ws, size_t ws_size,
                              hipStream_t stream)
{
    const float* img_feat = (const float*)d_in[0];
    const float* ques_feat = (const float*)d_in[1];
    const float* Wc = (const float*)d_in[2];
    const float* bc = (const float*)d_in[3];
    const float* Wq = (const float*)d_in[4];
    const float* bq = (const float*)d_in[5];
    const float* Wi = (const float*)d_in[6];
    const float* bi = (const float*)d_in[7];
    const float* wqa = (const float*)d_in[8];
    const float* bqa = (const float*)d_in[9];
    const float* wia = (const float*)d_in[10];
    const float* bia = (const float*)d_in[11];
    const float* g1 = (const float*)d_in[12]; const float* b1 = (const float*)d_in[13];
    const float* g2 = (const float*)d_in[14]; const float* b2 = (const float*)d_in[15];
    const float* g3 = (const float*)d_in[16]; const float* b3 = (const float*)d_in[17];
    const float* g4 = (const float*)d_in[18]; const float* b4 = (const float*)d_in[19];
    const float* g5 = (const float*)d_in[20]; const float* b5 = (const float*)d_in[21];

    // workspace layout (bytes)
    const size_t SZ_WP   = 1536u * 2048u * 2u;
    const size_t SZ_WQT  = 768u * 768u * 2u;
    const size_t SZ_IMG  = 51200ull * 1536u * 2u;     // bf16
    const size_t SZ_QE   = 7168u * 768u * 4u;
    const size_t SZ_WM   = 512u * 1400u * 4u;
    const size_t SZ_ABF  = 51200ull * 2048u * 2u;
    const size_t SZ_QBF  = 7168u * 768u * 2u;

    const size_t OFF_WP  = 0;
    const size_t OFF_WQT = OFF_WP + SZ_WP;
    const size_t OFF_IMG = OFF_WQT + SZ_WQT;
    const size_t OFF_QE  = OFF_IMG + SZ_IMG;
    const size_t OFF_WM  = OFF_QE + SZ_QE;
    const size_t OFF_ABF = OFF_WM + SZ_WM;
    const size_t OFF_QBF = OFF_ABF + SZ_ABF;
    const size_t NEED    = OFF_QBF + SZ_QBF;
    if (ws_size < NEED) return;

    char* ws = (char*)d_ws;
    unsigned short* Wp    = (unsigned short*)(ws + OFF_WP);
    unsigned short* Wqt   = (unsigned short*)(ws + OFF_WQT);
    unsigned short* imgCE = (unsigned short*)(ws + OFF_IMG);
    unsigned short* qe    = (unsigned short*)(ws + OFF_QE);
    unsigned short* Abf   = (unsigned short*)(ws + OFF_ABF);
    unsigned short* Qbf   = (unsigned short*)(ws + OFF_QBF);

    float* out_img = (float*)d_out;                   // [512][2048]
    float* out_q   = (float*)d_out + 512 * 2048;      // [512][768]

    hipLaunchKernelGGL(pack_t, dim3(32, 24), dim3(256), 0, stream, Wc, Wi, 768, Wp, 2048);
    hipLaunchKernelGGL(pack_t, dim3(12, 12), dim3(256), 0, stream, Wq, Wq, 768, Wqt, 768);
    hipLaunchKernelGGL(cvt2, dim3(2304), dim3(256), 0, stream,
                       img_feat, Abf, (long)(51200ull * 2048u / 8u),
                       ques_feat, Qbf, (long)(7168u * 768u / 8u), 2048);

    // imgCE(bf16) = img_feat @ [Wc|Wi] + [bc|bi]   (M=51200, N=1536, K=2048)
    hipLaunchKernelGGL(HIP_KERNEL_NAME(gemm8<1>), dim3(1200), dim3(512), 0, stream,
                       Abf, Wp, bc, bi, 768, (void*)imgCE, 1536, 2048, 6);
    // qe(bf16) = ques_feat @ Wq + bq               (M=7168, N=768, K=768)
    hipLaunchKernelGGL(HIP_KERNEL_NAME(gemm8<1>), dim3(84), dim3(512), 0, stream,
                       Qbf, Wqt, bq, bq, 768, (void*)qe, 768, 768, 3);

    hipLaunchKernelGGL(fused_kernel, dim3(512), dim3(256), 0, stream,
                       ques_feat, Qbf, qe, imgCE, Abf,
                       g1, b1, g2, b2, g3, b3, g4, b4, g5, b5,
                       wqa, bqa, wia, bia, out_img, out_q);
}

// Round 13
// 764.694 us; speedup vs baseline: 1.3504x; 1.2259x over previous
//
#include <hip/hip_runtime.h>

// ---------- types & helpers ----------
using f32x4     = __attribute__((ext_vector_type(4))) float;
using bf16x8    = __attribute__((ext_vector_type(8))) short;
using ushort4_t = __attribute__((ext_vector_type(4))) unsigned short;
using ushort8_t = __attribute__((ext_vector_type(8))) unsigned short;

__device__ __forceinline__ unsigned short f2bf(float f) {
    unsigned u = __builtin_bit_cast(unsigned, f);
    u += 0x7fffu + ((u >> 16) & 1u);   // RNE
    return (unsigned short)(u >> 16);
}
__device__ __forceinline__ float bf2f(unsigned short h) {
    return __builtin_bit_cast(float, (unsigned)h << 16);
}

__device__ __forceinline__ float wave_sum(float v) {
#pragma unroll
    for (int off = 32; off > 0; off >>= 1) v += __shfl_xor(v, off, 64);
    return v;
}
__device__ __forceinline__ float wave_max(float v) {
#pragma unroll
    for (int off = 32; off > 0; off >>= 1) v = fmaxf(v, __shfl_xor(v, off, 64));
    return v;
}

#define GLP(p)  ((const __attribute__((address_space(1))) void*)(p))
#define LDSP(p) ((__attribute__((address_space(3))) void*)(p))

// ---------- dual f32 -> bf16 bulk convert (two jobs, one launch) ----------
__global__ __launch_bounds__(256) void cvt2(
    const float* __restrict__ in0, unsigned short* __restrict__ out0, long n80,
    const float* __restrict__ in1, unsigned short* __restrict__ out1, long n81, int split)
{
    const float* in; unsigned short* out; long n8, i, stride;
    if ((int)blockIdx.x < split) {
        in = in0; out = out0; n8 = n80;
        i = (long)blockIdx.x * 256 + threadIdx.x; stride = (long)split * 256;
    } else {
        in = in1; out = out1; n8 = n81;
        i = (long)(blockIdx.x - split) * 256 + threadIdx.x;
        stride = (long)(gridDim.x - split) * 256;
    }
    for (; i < n8; i += stride) {
        const float4* p = (const float4*)(in + i * 8);
        float4 a = p[0], b = p[1];
        ushort8_t v;
        v[0] = f2bf(a.x); v[1] = f2bf(a.y); v[2] = f2bf(a.z); v[3] = f2bf(a.w);
        v[4] = f2bf(b.x); v[5] = f2bf(b.y); v[6] = f2bf(b.z); v[7] = f2bf(b.w);
        *(ushort8_t*)(out + i * 8) = v;
    }
}

// ---------- coalesced LDS-tiled weight transpose -> bf16 [N][K] ----------
__global__ __launch_bounds__(256) void pack_t(
    const float* __restrict__ S0, const float* __restrict__ S1, int nsplit,
    unsigned short* __restrict__ D, int K)
{
    __shared__ float t[64][65];
    const int k0 = blockIdx.x * 64, n0 = blockIdx.y * 64;
    const float* S = (n0 < nsplit) ? S0 : S1;
    const int nb = (n0 < nsplit) ? n0 : n0 - nsplit;
    const int c = threadIdx.x & 63, r4 = threadIdx.x >> 6;
#pragma unroll
    for (int it = 0; it < 16; ++it) {
        int r = it * 4 + r4;
        t[r][c] = S[(size_t)(k0 + r) * nsplit + nb + c];
    }
    __syncthreads();
#pragma unroll
    for (int it = 0; it < 16; ++it) {
        int rn = it * 4 + r4;
        D[(size_t)(n0 + rn) * K + k0 + c] = f2bf(t[c][rn]);
    }
}

// ---------- 256x256 bf16 GEMM, 8-phase (FROZEN, R7/R8 config) ----------
template <int OUTBF>
__global__ __launch_bounds__(512, 1) void gemm8(
    const unsigned short* __restrict__ A, const unsigned short* __restrict__ Bt,
    const float* __restrict__ bias0, const float* __restrict__ bias1, int nsplit,
    void* __restrict__ Cv, int N, int K, int NTN)
{
    __shared__ unsigned short LA[2][2][8192];
    __shared__ unsigned short LB[2][2][8192];
    const int tid = threadIdx.x, lane = tid & 63, wid = tid >> 6;

    int nwg = (int)gridDim.x, bid = (int)blockIdx.x;
    if ((nwg & 7) == 0) { int cpx = nwg >> 3; bid = (bid & 7) * cpx + (bid >> 3); }  // T1
    const int tn = bid % NTN, tm = bid / NTN;
    const size_t m0 = (size_t)tm * 256, n0 = (size_t)tn * 256;
    const int NT = K >> 6;
    const int NIT = NT >> 1;

    const int wr = wid >> 2, wc = wid & 3;
    const int hb = wc >> 1;
    const int fr = lane & 15, fs = lane >> 4;

    const int r0 = tid >> 3, s0 = ((tid & 7) - r0) & 7;
    const int r1 = r0 + 64,  s1 = ((tid & 7) - r1) & 7;
    const unsigned short* pA[2][2];
    const unsigned short* pB[2][2];
#pragma unroll
    for (int h = 0; h < 2; ++h) {
        pA[h][0] = A  + (m0 + h * 128 + r0) * K + s0 * 8;
        pA[h][1] = A  + (m0 + h * 128 + r1) * K + s1 * 8;
        pB[h][0] = Bt + (n0 + h * 128 + r0) * K + s0 * 8;
        pB[h][1] = Bt + (n0 + h * 128 + r1) * K + s1 * 8;
    }
    const int d0 = tid * 8, d1 = (tid + 512) * 8;

#define STG_A(h, t, B_) do { \
    __builtin_amdgcn_global_load_lds(GLP(pA[h][0] + (size_t)(t) * 64), LDSP(&LA[B_][h][d0]), 16, 0, 0); \
    __builtin_amdgcn_global_load_lds(GLP(pA[h][1] + (size_t)(t) * 64), LDSP(&LA[B_][h][d1]), 16, 0, 0); \
} while (0)
#define STG_B(h, t, B_) do { \
    __builtin_amdgcn_global_load_lds(GLP(pB[h][0] + (size_t)(t) * 64), LDSP(&LB[B_][h][d0]), 16, 0, 0); \
    __builtin_amdgcn_global_load_lds(GLP(pB[h][1] + (size_t)(t) * 64), LDSP(&LB[B_][h][d1]), 16, 0, 0); \
} while (0)

    int offA[2][4], offB[2][2];
#pragma unroll
    for (int mq = 0; mq < 2; ++mq)
#pragma unroll
        for (int mfl = 0; mfl < 4; ++mfl) {
            int r = mq * 64 + mfl * 16 + fr;
            offA[mq][mfl] = r * 64 + ((fs + r) & 7) * 8;
        }
#pragma unroll
    for (int nq = 0; nq < 2; ++nq)
#pragma unroll
        for (int nfl = 0; nfl < 2; ++nfl) {
            int r = (wc & 1) * 64 + nq * 32 + nfl * 16 + fr;
            offB[nq][nfl] = r * 64 + ((fs + r) & 7) * 8;
        }

#define LDA_SUB(B_, mq) do { \
    _Pragma("unroll") \
    for (int mfl = 0; mfl < 4; ++mfl) { \
        av[mfl][0] = *(const bf16x8*)&LA[B_][wr][offA[mq][mfl]]; \
        av[mfl][1] = *(const bf16x8*)&LA[B_][wr][offA[mq][mfl] ^ 32]; \
    } } while (0)
#define LDB_SUB(B_, nq, bv) do { \
    _Pragma("unroll") \
    for (int nfl = 0; nfl < 2; ++nfl) { \
        bv[nfl][0] = *(const bf16x8*)&LB[B_][hb][offB[nq][nfl]]; \
        bv[nfl][1] = *(const bf16x8*)&LB[B_][hb][offB[nq][nfl] ^ 32]; \
    } } while (0)
#define MMA_Q(mq, nq, bv) do { \
    _Pragma("unroll") \
    for (int ks = 0; ks < 2; ++ks) \
    _Pragma("unroll") \
    for (int mfl = 0; mfl < 4; ++mfl) \
    _Pragma("unroll") \
    for (int nfl = 0; nfl < 2; ++nfl) \
        acc[mq * 4 + mfl][nq * 2 + nfl] = __builtin_amdgcn_mfma_f32_16x16x32_bf16( \
            av[mfl][ks], bv[nfl][ks], acc[mq * 4 + mfl][nq * 2 + nfl], 0, 0, 0); \
    } while (0)
#define BAR  __builtin_amdgcn_s_barrier()
#define SCB  __builtin_amdgcn_sched_barrier(0)
#define LGKM0 do { asm volatile("s_waitcnt lgkmcnt(0)" ::: "memory"); SCB; } while (0)
#define PRIO1 __builtin_amdgcn_s_setprio(1)
#define PRIO0 __builtin_amdgcn_s_setprio(0)

    f32x4 acc[8][4];
#pragma unroll
    for (int i = 0; i < 8; ++i)
#pragma unroll
        for (int j = 0; j < 4; ++j) acc[i][j] = (f32x4){0.f, 0.f, 0.f, 0.f};

    STG_A(0, 0, 0); STG_A(1, 0, 0); STG_B(0, 0, 0); STG_B(1, 0, 0);
    STG_B(0, 1, 1); STG_B(1, 1, 1); STG_A(0, 1, 1);
    asm volatile("s_waitcnt vmcnt(6)" ::: "memory");
    SCB; BAR;

    for (int i = 0; i < NIT; ++i) {
        const int t0 = 2 * i, t1 = 2 * i + 1;
        const bool st = (i + 1 < NIT);
        bf16x8 av[4][2], bv0[2][2], bv1[2][2];

        LDA_SUB(0, 0); LDB_SUB(0, 0, bv0);
        STG_A(1, t1, 1);
        BAR; LGKM0;
        PRIO1; MMA_Q(0, 0, bv0); PRIO0;
        BAR;

        LDB_SUB(0, 1, bv1);
        BAR; LGKM0;
        PRIO1; MMA_Q(0, 1, bv1); PRIO0;
        BAR;

        LDA_SUB(0, 1);
        if (st) STG_B(0, t0 + 2, 0);
        BAR; LGKM0;
        PRIO1; MMA_Q(1, 1, bv1); PRIO0;
        BAR;

        if (st) { STG_B(1, t0 + 2, 0); STG_A(0, t0 + 2, 0); }
        BAR;
        PRIO1; MMA_Q(1, 0, bv0); PRIO0;
        if (st) asm volatile("s_waitcnt vmcnt(6)" ::: "memory");
        else    asm volatile("s_waitcnt vmcnt(0)" ::: "memory");
        SCB; BAR;

        LDA_SUB(1, 0); LDB_SUB(1, 0, bv0);
        if (st) STG_A(1, t0 + 2, 0);
        BAR; LGKM0;
        PRIO1; MMA_Q(0, 0, bv0); PRIO0;
        BAR;

        LDB_SUB(1, 1, bv1);
        BAR; LGKM0;
        PRIO1; MMA_Q(0, 1, bv1); PRIO0;
        BAR;

        LDA_SUB(1, 1);
        if (st) STG_B(0, t1 + 2, 1);
        BAR; LGKM0;
        PRIO1; MMA_Q(1, 1, bv1); PRIO0;
        BAR;

        if (st) { STG_B(1, t1 + 2, 1); STG_A(0, t1 + 2, 1); }
        BAR;
        PRIO1; MMA_Q(1, 0, bv0); PRIO0;
        if (st) asm volatile("s_waitcnt vmcnt(6)" ::: "memory");
        else    asm volatile("s_waitcnt vmcnt(0)" ::: "memory");
        SCB; BAR;
    }

#undef STG_A
#undef STG_B
#undef LDA_SUB
#undef LDB_SUB
#undef MMA_Q
#undef BAR
#undef SCB
#undef LGKM0
#undef PRIO1
#undef PRIO0

    const int wm = wr * 128, wn = wc * 64;
#pragma unroll
    for (int nf = 0; nf < 4; ++nf) {
        int col = (int)n0 + wn + nf * 16 + fr;
        float bs = (col < nsplit) ? bias0[col] : bias1[col - nsplit];
#pragma unroll
        for (int mf = 0; mf < 8; ++mf) {
            size_t rowb = m0 + wm + mf * 16 + fs * 4;
#pragma unroll
            for (int r = 0; r < 4; ++r) {
                float v = acc[mf][nf][r] + bs;
                if (OUTBF) ((unsigned short*)Cv)[(rowb + r) * N + col] = f2bf(v);
                else       ((float*)Cv)[(rowb + r) * N + col] = v;
            }
        }
    }
}

// ---------- fused per-b kernel (single role, bf16 LDS buf; R10 known-good) ----------
__global__ __launch_bounds__(256) void fused_kernel(
    const float* __restrict__ qf_g, const unsigned short* __restrict__ qbf,
    const unsigned short* __restrict__ qe_g, const unsigned short* __restrict__ imgCE,
    const unsigned short* __restrict__ imf_bf,
    const float* __restrict__ g1, const float* __restrict__ b1,
    const float* __restrict__ g2, const float* __restrict__ b2,
    const float* __restrict__ g3, const float* __restrict__ b3,
    const float* __restrict__ g4, const float* __restrict__ b4,
    const float* __restrict__ g5, const float* __restrict__ b5,
    const float* __restrict__ wqa, const float* __restrict__ bqa,
    const float* __restrict__ wia, const float* __restrict__ bia,
    float* __restrict__ out_i, float* __restrict__ out_q)
{
    const int b = blockIdx.x;
    const int tid = threadIdx.x, lane = tid & 63, wid = tid >> 6;
    __shared__ unsigned short buf[14 * 768];   // bf16: qbf (phase 1) then qe (phases 2-3)
    __shared__ float wms[14 * 100];
    __shared__ float red[4][28];
    __shared__ float mu_s[14], rs_s[14], qa_s[14], qw_s[14];
    __shared__ float mu2_s[10], rs2_s[10];
    __shared__ float ia_s[100], iw_s[100];

    // ===== phase 1: wm =====
    {
        const ushort8_t* src = (const ushort8_t*)(qbf + (size_t)b * 14 * 768);
        for (int i = tid; i < 14 * 768 / 8; i += 256) *(ushort8_t*)&buf[i * 8] = src[i];
    }
    __syncthreads();
    {
        float rcur[12], rnxt[12];
        {
            const unsigned short* row = imgCE + ((size_t)b * 100 + wid) * 1536;
#pragma unroll
            for (int j = 0; j < 12; ++j) rnxt[j] = bf2f(row[lane + 64 * j]);
        }
        for (int n = wid; n < 100; n += 4) {
#pragma unroll
            for (int j = 0; j < 12; ++j) rcur[j] = rnxt[j];
            if (n + 4 < 100) {
                const unsigned short* row = imgCE + ((size_t)b * 100 + n + 4) * 1536;
#pragma unroll
                for (int j = 0; j < 12; ++j) rnxt[j] = bf2f(row[lane + 64 * j]);
            }
            for (int t = 0; t < 14; ++t) {
                const unsigned short* q = buf + t * 768;
                float s = 0.f;
#pragma unroll
                for (int j = 0; j < 12; ++j) s = fmaf(rcur[j], bf2f(q[lane + 64 * j]), s);
                s = wave_sum(s);
                if (lane == 0) wms[t * 100 + n] = s;
            }
        }
    }
    __syncthreads();
    for (int t = wid; t < 14; t += 4) {
        float x0 = wms[t * 100 + lane];
        float x1 = (lane + 64 < 100) ? wms[t * 100 + lane + 64] : 0.f;
        float s = wave_sum(x0 + x1);
        float q = wave_sum(x0 * x0 + x1 * x1);
        float mu = s * (1.f / 100.f);
        float var = q * (1.f / 100.f) - mu * mu;
        float rs = rsqrtf(var + 1e-3f);
        {
            float v = (x0 - mu) * rs * g1[lane] + b1[lane];
            wms[t * 100 + lane] = v > 0.f ? v : 0.f;
        }
        if (lane + 64 < 100) {
            float v = (x1 - mu) * rs * g1[lane + 64] + b1[lane + 64];
            wms[t * 100 + lane + 64] = v > 0.f ? v : 0.f;
        }
    }
    // restage buf with qe (bf16 raw copy)
    {
        const ushort8_t* src = (const ushort8_t*)(qe_g + (size_t)b * 14 * 768);
        for (int i = tid; i < 14 * 768 / 8; i += 256) *(ushort8_t*)&buf[i * 8] = src[i];
    }
    __syncthreads();

    // ===== phase 2: ques path =====
    {
        float a0[14], a1[14], a2[14];
#pragma unroll
        for (int t = 0; t < 14; ++t) { a0[t] = 0.f; a1[t] = 0.f; a2[t] = 0.f; }

        const unsigned short* ie_base = imgCE + (size_t)b * 100 * 1536 + 768;  // img_embed
        float e0n = bf2f(ie_base[tid]), e1n = bf2f(ie_base[tid + 256]), e2n = bf2f(ie_base[tid + 512]);
        for (int n = 0; n < 100; ++n) {
            float e0 = e0n, e1 = e1n, e2 = e2n;
            if (n < 99) {
                const unsigned short* ie = ie_base + (size_t)(n + 1) * 1536;
                e0n = bf2f(ie[tid]); e1n = bf2f(ie[tid + 256]); e2n = bf2f(ie[tid + 512]);
            }
#pragma unroll
            for (int t = 0; t < 14; ++t) {
                float w = wms[t * 100 + n];
                a0[t] = fmaf(w, e0, a0[t]); a1[t] = fmaf(w, e1, a1[t]); a2[t] = fmaf(w, e2, a2[t]);
            }
        }
#pragma unroll
        for (int t = 0; t < 14; ++t) {
            a0[t] += bf2f(buf[t * 768 + tid]);
            a1[t] += bf2f(buf[t * 768 + tid + 256]);
            a2[t] += bf2f(buf[t * 768 + tid + 512]);
        }
#pragma unroll
        for (int t = 0; t < 14; ++t) {
            float s = wave_sum(a0[t] + a1[t] + a2[t]);
            float q = wave_sum(a0[t] * a0[t] + a1[t] * a1[t] + a2[t] * a2[t]);
            if (lane == 0) { red[wid][t] = s; red[wid][14 + t] = q; }
        }
        __syncthreads();
        if (tid < 14) {
            float s = red[0][tid] + red[1][tid] + red[2][tid] + red[3][tid];
            float q = red[0][14 + tid] + red[1][14 + tid] + red[2][14 + tid] + red[3][14 + tid];
            float mu = s * (1.f / 768.f);
            float var = q * (1.f / 768.f) - mu * mu;
            mu_s[tid] = mu; rs_s[tid] = rsqrtf(var + 1e-3f);
        }
        __syncthreads();

        float ga = g2[tid], ba = b2[tid], gb = g2[tid + 256], bb = b2[tid + 256],
              gc = g2[tid + 512], bc_ = b2[tid + 512];
        float w0 = wqa[tid], w1 = wqa[tid + 256], w2 = wqa[tid + 512];
#pragma unroll
        for (int t = 0; t < 14; ++t) {
            float mu = mu_s[t], rs = rs_s[t];
            float v0 = fmaxf((a0[t] - mu) * rs * ga + ba, 0.f);
            float v1 = fmaxf((a1[t] - mu) * rs * gb + bb, 0.f);
            float v2 = fmaxf((a2[t] - mu) * rs * gc + bc_, 0.f);
            float p = wave_sum(v0 * w0 + v1 * w1 + v2 * w2);
            if (lane == 0) red[wid][t] = p;
        }
        __syncthreads();
        if (tid < 14) qa_s[tid] = red[0][tid] + red[1][tid] + red[2][tid] + red[3][tid] + bqa[0];
        __syncthreads();
        if (tid == 0) {
            float s = 0.f;
            for (int t = 0; t < 14; ++t) s += qa_s[t];
            float mu = s * (1.f / 14.f);
            float q = 0.f;
            for (int t = 0; t < 14; ++t) { float d = qa_s[t] - mu; q += d * d; }
            float rs = rsqrtf(q * (1.f / 14.f) + 1e-3f);
            float e[14], mx = -1e30f;
            for (int t = 0; t < 14; ++t) { e[t] = (qa_s[t] - mu) * rs * g3[t] + b3[t]; mx = fmaxf(mx, e[t]); }
            float se = 0.f;
            for (int t = 0; t < 14; ++t) { e[t] = expf(e[t] - mx); se += e[t]; }
            float inv = 1.f / se;
            for (int t = 0; t < 14; ++t) qw_s[t] = e[t] * inv;
        }
        __syncthreads();

        const float* qf = qf_g + (size_t)b * 14 * 768;
#pragma unroll
        for (int c = 0; c < 3; ++c) {
            int h = tid + c * 256;
            float o = 0.f;
#pragma unroll
            for (int t = 0; t < 14; ++t) o = fmaf(qw_s[t], qf[t * 768 + h], o);
            out_q[(size_t)b * 768 + h] = o;
        }
    }
    __syncthreads();

    // ===== phase 3: img path =====
    {
        float g4a = g4[tid], b4a = b4[tid], g4b = g4[tid + 256], b4b = b4[tid + 256],
              g4c = g4[tid + 512], b4c = b4[tid + 512];
        float wa = wia[tid], wb = wia[tid + 256], wc_ = wia[tid + 512];

        for (int g = 0; g < 10; ++g) {
            float ge0[10], ge1[10], ge2[10];
#pragma unroll
            for (int i = 0; i < 10; ++i) {
                const unsigned short* ie = imgCE + ((size_t)b * 100 + g * 10 + i) * 1536 + 768;
                ge0[i] = bf2f(ie[tid]); ge1[i] = bf2f(ie[tid + 256]); ge2[i] = bf2f(ie[tid + 512]);
            }
            float t0[10], t1[10], t2[10];
#pragma unroll
            for (int i = 0; i < 10; ++i) { t0[i] = 0.f; t1[i] = 0.f; t2[i] = 0.f; }
#pragma unroll
            for (int t = 0; t < 14; ++t) {
                float q0 = bf2f(buf[t * 768 + tid]), q1 = bf2f(buf[t * 768 + tid + 256]),
                      q2 = bf2f(buf[t * 768 + tid + 512]);
#pragma unroll
                for (int i = 0; i < 10; ++i) {
                    float w = wms[t * 100 + g * 10 + i];
                    t0[i] = fmaf(w, q0, t0[i]); t1[i] = fmaf(w, q1, t1[i]); t2[i] = fmaf(w, q2, t2[i]);
                }
            }
#pragma unroll
            for (int i = 0; i < 10; ++i) {
                t0[i] += ge0[i]; t1[i] += ge1[i]; t2[i] += ge2[i];
                float s = wave_sum(t0[i] + t1[i] + t2[i]);
                float q = wave_sum(t0[i] * t0[i] + t1[i] * t1[i] + t2[i] * t2[i]);
                if (lane == 0) { red[wid][i] = s; red[wid][10 + i] = q; }
            }
            __syncthreads();
            if (tid < 10) {
                float s = red[0][tid] + red[1][tid] + red[2][tid] + red[3][tid];
                float q = red[0][10 + tid] + red[1][10 + tid] + red[2][10 + tid] + red[3][10 + tid];
                float mu = s * (1.f / 768.f);
                float var = q * (1.f / 768.f) - mu * mu;
                mu2_s[tid] = mu; rs2_s[tid] = rsqrtf(var + 1e-3f);
            }
            __syncthreads();
#pragma unroll
            for (int i = 0; i < 10; ++i) {
                float mu = mu2_s[i], rs = rs2_s[i];
                float v0 = fmaxf((t0[i] - mu) * rs * g4a + b4a, 0.f);
                float v1 = fmaxf((t1[i] - mu) * rs * g4b + b4b, 0.f);
                float v2 = fmaxf((t2[i] - mu) * rs * g4c + b4c, 0.f);
                float p = wave_sum(v0 * wa + v1 * wb + v2 * wc_);
                if (lane == 0) red[wid][i] = p;
            }
            __syncthreads();
            if (tid < 10) ia_s[g * 10 + tid] = red[0][tid] + red[1][tid] + red[2][tid] + red[3][tid] + bia[0];
            __syncthreads();
        }

        if (wid == 0) {
            float x0 = ia_s[lane];
            float x1 = (lane + 64 < 100) ? ia_s[lane + 64] : 0.f;
            float s = wave_sum(x0 + x1);
            float q = wave_sum(x0 * x0 + x1 * x1);
            float mu = s * 0.01f;
            float var = q * 0.01f - mu * mu;
            float rs = rsqrtf(var + 1e-3f);
            float v0 = (x0 - mu) * rs * g5[lane] + b5[lane];
            float v1 = (lane + 64 < 100) ? (x1 - mu) * rs * g5[lane + 64] + b5[lane + 64] : -1e30f;
            float mx = wave_max(fmaxf(v0, v1));
            float e0 = expf(v0 - mx);
            float e1 = (lane + 64 < 100) ? expf(v1 - mx) : 0.f;
            float se = wave_sum(e0 + e1);
            float inv = 1.f / se;
            iw_s[lane] = e0 * inv;
            if (lane + 64 < 100) iw_s[lane + 64] = e1 * inv;
        }
        __syncthreads();

        const unsigned short* imf = imf_bf + (size_t)b * 100 * 2048;
        float acc8[8];
#pragma unroll
        for (int j = 0; j < 8; ++j) acc8[j] = 0.f;
        for (int n = 0; n < 100; ++n) {
            ushort8_t v = *(const ushort8_t*)(imf + (size_t)n * 2048 + tid * 8);
            float w = iw_s[n];
#pragma unroll
            for (int j = 0; j < 8; ++j) acc8[j] = fmaf(w, bf2f(v[j]), acc8[j]);
        }
        float4* dst = (float4*)(out_i + (size_t)b * 2048);
        float4 oA = {acc8[0], acc8[1], acc8[2], acc8[3]};
        float4 oB = {acc8[4], acc8[5], acc8[6], acc8[7]};
        dst[tid * 2] = oA; dst[tid * 2 + 1] = oB;
    }
}

// ---------- launch ----------
extern "C" void kernel_launch(void* const* d_in, const int* in_sizes, int n_in,
                              void* d_out, int out_size, void* d_ws, size_t ws_size,
                              hipStream_t stream)
{
    const float* img_feat = (const float*)d_in[0];
    const float* ques_feat = (const float*)d_in[1];
    const float* Wc = (const float*)d_in[2];
    const float* bc = (const float*)d_in[3];
    const float* Wq = (const float*)d_in[4];
    const float* bq = (const float*)d_in[5];
    const float* Wi = (const float*)d_in[6];
    const float* bi = (const float*)d_in[7];
    const float* wqa = (const float*)d_in[8];
    const float* bqa = (const float*)d_in[9];
    const float* wia = (const float*)d_in[10];
    const float* bia = (const float*)d_in[11];
    const float* g1 = (const float*)d_in[12]; const float* b1 = (const float*)d_in[13];
    const float* g2 = (const float*)d_in[14]; const float* b2 = (const float*)d_in[15];
    const float* g3 = (const float*)d_in[16]; const float* b3 = (const float*)d_in[17];
    const float* g4 = (const float*)d_in[18]; const float* b4 = (const float*)d_in[19];
    const float* g5 = (const float*)d_in[20]; const float* b5 = (const float*)d_in[21];

    // workspace layout (bytes)
    const size_t SZ_WP   = 1536u * 2048u * 2u;
    const size_t SZ_WQT  = 768u * 768u * 2u;
    const size_t SZ_IMG  = 51200ull * 1536u * 2u;     // bf16
    const size_t SZ_QE   = 7168u * 768u * 4u;
    const size_t SZ_WM   = 512u * 1400u * 4u;
    const size_t SZ_ABF  = 51200ull * 2048u * 2u;
    const size_t SZ_QBF  = 7168u * 768u * 2u;

    const size_t OFF_WP  = 0;
    const size_t OFF_WQT = OFF_WP + SZ_WP;
    const size_t OFF_IMG = OFF_WQT + SZ_WQT;
    const size_t OFF_QE  = OFF_IMG + SZ_IMG;
    const size_t OFF_WM  = OFF_QE + SZ_QE;
    const size_t OFF_ABF = OFF_WM + SZ_WM;
    const size_t OFF_QBF = OFF_ABF + SZ_ABF;
    const size_t NEED    = OFF_QBF + SZ_QBF;
    if (ws_size < NEED) return;

    char* ws = (char*)d_ws;
    unsigned short* Wp    = (unsigned short*)(ws + OFF_WP);
    unsigned short* Wqt   = (unsigned short*)(ws + OFF_WQT);
    unsigned short* imgCE = (unsigned short*)(ws + OFF_IMG);
    unsigned short* qe    = (unsigned short*)(ws + OFF_QE);
    unsigned short* Abf   = (unsigned short*)(ws + OFF_ABF);
    unsigned short* Qbf   = (unsigned short*)(ws + OFF_QBF);

    float* out_img = (float*)d_out;                   // [512][2048]
    float* out_q   = (float*)d_out + 512 * 2048;      // [512][768]

    hipLaunchKernelGGL(pack_t, dim3(32, 24), dim3(256), 0, stream, Wc, Wi, 768, Wp, 2048);
    hipLaunchKernelGGL(pack_t, dim3(12, 12), dim3(256), 0, stream, Wq, Wq, 768, Wqt, 768);
    hipLaunchKernelGGL(cvt2, dim3(2304), dim3(256), 0, stream,
                       img_feat, Abf, (long)(51200ull * 2048u / 8u),
                       ques_feat, Qbf, (long)(7168u * 768u / 8u), 2048);

    // imgCE(bf16) = img_feat @ [Wc|Wi] + [bc|bi]   (M=51200, N=1536, K=2048)
    hipLaunchKernelGGL(HIP_KERNEL_NAME(gemm8<1>), dim3(1200), dim3(512), 0, stream,
                       Abf, Wp, bc, bi, 768, (void*)imgCE, 1536, 2048, 6);
    // qe(bf16) = ques_feat @ Wq + bq               (M=7168, N=768, K=768)
    hipLaunchKernelGGL(HIP_KERNEL_NAME(gemm8<1>), dim3(84), dim3(512), 0, stream,
                       Qbf, Wqt, bq, bq, 768, (void*)qe, 768, 768, 3);

    hipLaunchKernelGGL(fused_kernel, dim3(512), dim3(256), 0, stream,
                       ques_feat, Qbf, qe, imgCE, Abf,
                       g1, b1, g2, b2, g3, b3, g4, b4, g5, b5,
                       wqa, bqa, wia, bia, out_img, out_q);
}